// Round 2
// baseline (120.033 us; speedup 1.0000x reference)
//
#include <hip/hip_runtime.h>
#include <hip/hip_bf16.h>

// Problem constants (reference: B=2048, N_BINS=200, D=128, G=100)
#define NB  200
#define BSZ 2048
#define DD  128
#define GG  100

typedef __attribute__((ext_vector_type(8))) short  short8;  // 8 bf16 = 4 VGPR (MFMA A/B frag)
typedef __attribute__((ext_vector_type(4))) float  f32x4;   // MFMA C/D frag

// round-to-nearest-even f32 -> bf16, two at a time packed into a dword
__device__ __forceinline__ unsigned f2bf_pack(float lo, float hi) {
    unsigned ulo = __builtin_bit_cast(unsigned, lo);
    ulo += 0x7FFFu + ((ulo >> 16) & 1u);
    unsigned uhi = __builtin_bit_cast(unsigned, hi);
    uhi += 0x7FFFu + ((uhi >> 16) & 1u);
    return (ulo >> 16) | (uhi & 0xFFFF0000u);
}

// One block: bin n = blockIdx.y, 128 batch rows starting at blockIdx.x*128.
// 4 waves x 32 rows each. Full G covered by 7 col-frags of 16 (last masked).
// K = 128 = 4 MFMA k-steps of 32, fully unrolled.
__global__ __launch_bounds__(256) void mtl_heads_kernel(
    const float* __restrict__ X,     // [B][NB][DD]
    const float* __restrict__ W,     // [NB][GG][DD]
    const float* __restrict__ Bias,  // [NB][GG]
    float* __restrict__ Out)         // [NB][B][GG] flattened
{
    const int n     = blockIdx.y;
    const int mtile = blockIdx.x;
    const int tid   = threadIdx.x;
    const int lane  = tid & 63;
    const int wid   = tid >> 6;
    const int l15   = lane & 15;
    const int lhi   = lane >> 4;   // 0..3

    // W tile in LDS: bf16 [112 rows][128 k] = 28 KB, XOR-swizzled (G4 fix:
    // row-major 256B rows -> byte ^= (row&7)<<4, else ds_read_b128 is 16-way conflicted)
    __shared__ __align__(16) char smem[112 * 256];

    // ---- Stage W[n] (100x128 f32 -> bf16 LDS), rows 100..111 zero-padded ----
    {
        const int rsub = tid >> 4;          // 0..15
        const int k0   = (tid & 15) * 8;    // element offset 0,8,...,120
        #pragma unroll
        for (int it = 0; it < 7; ++it) {
            const int row = it * 16 + rsub; // 0..111
            int4 pack = make_int4(0, 0, 0, 0);
            if (row < GG) {
                const float* src = W + ((size_t)n * GG + row) * DD + k0;
                const f32x4 a = *reinterpret_cast<const f32x4*>(src);
                const f32x4 b = *reinterpret_cast<const f32x4*>(src + 4);
                pack.x = f2bf_pack(a[0], a[1]);
                pack.y = f2bf_pack(a[2], a[3]);
                pack.z = f2bf_pack(b[0], b[1]);
                pack.w = f2bf_pack(b[2], b[3]);
            }
            const int off = row * 256 + ((k0 * 2) ^ ((row & 7) << 4));
            *reinterpret_cast<int4*>(smem + off) = pack;  // ds_write_b128, conflict-free
        }
    }
    __syncthreads();  // the only barrier

    // ---- Load A fragments global->reg with on-the-fly bf16 convert ----
    // A-frag layout (16x16x32): lane holds row = l&15, k = (l>>4)*8 + j
    const int rowbase = mtile * 128 + wid * 32;
    short8 areg[2][4];
    #pragma unroll
    for (int rf = 0; rf < 2; ++rf) {
        const float* xrow = X + ((size_t)(rowbase + rf * 16 + l15) * NB + n) * DD + lhi * 8;
        #pragma unroll
        for (int ks = 0; ks < 4; ++ks) {
            const f32x4 a = *reinterpret_cast<const f32x4*>(xrow + ks * 32);
            const f32x4 b = *reinterpret_cast<const f32x4*>(xrow + ks * 32 + 4);
            int4 pk;
            pk.x = f2bf_pack(a[0], a[1]);
            pk.y = f2bf_pack(a[2], a[3]);
            pk.z = f2bf_pack(b[0], b[1]);
            pk.w = f2bf_pack(b[2], b[3]);
            areg[rf][ks] = __builtin_bit_cast(short8, pk);
        }
    }

    // ---- MFMA main: 2 row-frags x 7 col-frags x 4 k-steps = 56 MFMA/wave ----
    f32x4 acc[2][7];
    #pragma unroll
    for (int rf = 0; rf < 2; ++rf)
        #pragma unroll
        for (int cf = 0; cf < 7; ++cf)
            acc[rf][cf] = (f32x4){0.f, 0.f, 0.f, 0.f};

    #pragma unroll
    for (int cf = 0; cf < 7; ++cf) {
        const int g    = cf * 16 + l15;      // B-frag: col = l&15 (gene row of W)
        const int rowb = g * 256;
        const int swz  = (g & 7) << 4;
        #pragma unroll
        for (int ks = 0; ks < 4; ++ks) {
            const int off = rowb + (((lhi * 16) + ks * 64) ^ swz);
            const int4 braw = *reinterpret_cast<const int4*>(smem + off);  // ds_read_b128
            const short8 bfrag = __builtin_bit_cast(short8, braw);
            acc[0][cf] = __builtin_amdgcn_mfma_f32_16x16x32_bf16(areg[0][ks], bfrag, acc[0][cf], 0, 0, 0);
            acc[1][cf] = __builtin_amdgcn_mfma_f32_16x16x32_bf16(areg[1][ks], bfrag, acc[1][cf], 0, 0, 0);
        }
    }

    // ---- Epilogue: C/D layout col = l&15, row = (l>>4)*4 + j ----
    #pragma unroll
    for (int cf = 0; cf < 7; ++cf) {
        const int g = cf * 16 + l15;
        if (g < GG) {
            const float bias = Bias[n * GG + g];
            #pragma unroll
            for (int rf = 0; rf < 2; ++rf) {
                const size_t obase = ((size_t)n * BSZ + rowbase + rf * 16 + lhi * 4) * GG + g;
                #pragma unroll
                for (int j = 0; j < 4; ++j) {
                    Out[obase + (size_t)j * GG] = acc[rf][cf][j] + bias;
                }
            }
        }
    }
}

extern "C" void kernel_launch(void* const* d_in, const int* in_sizes, int n_in,
                              void* d_out, int out_size, void* d_ws, size_t ws_size,
                              hipStream_t stream) {
    (void)in_sizes; (void)n_in; (void)out_size; (void)d_ws; (void)ws_size;
    const float* X    = (const float*)d_in[0];
    const float* W    = (const float*)d_in[1];
    const float* Bias = (const float*)d_in[2];
    float* Out        = (float*)d_out;
    dim3 grid(BSZ / 128, NB);  // 16 x 200 = 3200 blocks
    mtl_heads_kernel<<<grid, 256, 0, stream>>>(X, W, Bias, Out);
}

// Round 4
// 88.390 us; speedup vs baseline: 1.3580x; 1.3580x over previous
//
#include <hip/hip_runtime.h>
#include <hip/hip_bf16.h>

// Problem constants (reference: B=2048, N_BINS=200, D=128, G=100)
#define NB   200
#define BSZ  2048
#define DD   128
#define GG   100
#define WROWS 112                 // gene rows padded to 7 frags of 16
#define ROWB  256                 // bytes per LDS W row (128 bf16)
#define WIMG  (WROWS * ROWB)      // 28672 B per-bin W image

typedef __attribute__((ext_vector_type(8))) short  short8;  // 8 bf16 (MFMA A/B frag)
typedef __attribute__((ext_vector_type(4))) float  f32x4;   // MFMA C/D frag

// round-to-nearest-even f32 -> bf16, two at a time packed into a dword
__device__ __forceinline__ unsigned f2bf_pack(float lo, float hi) {
    unsigned ulo = __builtin_bit_cast(unsigned, lo);
    ulo += 0x7FFFu + ((ulo >> 16) & 1u);
    unsigned uhi = __builtin_bit_cast(unsigned, hi);
    uhi += 0x7FFFu + ((uhi >> 16) & 1u);
    return (ulo >> 16) | (uhi & 0xFFFF0000u);
}

__device__ __forceinline__ void gload_lds16(const void* g, void* l) {
    __builtin_amdgcn_global_load_lds(
        (const __attribute__((address_space(1))) unsigned int*)g,
        (__attribute__((address_space(3))) unsigned int*)l, 16, 0, 0);
}

// Wave-level LDS sync: drain LDS ops, forbid compiler/scheduler motion.
// waitcnt imm 0xC07F: vmcnt=63, expcnt=7, lgkmcnt=0 (wait LDS only).
#define WAIT_LGKM0() do { asm volatile("" ::: "memory");     \
                          __builtin_amdgcn_s_waitcnt(0xC07F);\
                          __builtin_amdgcn_sched_barrier(0); \
                          __builtin_amdgcn_wave_barrier();   \
                          asm volatile("" ::: "memory"); } while (0)

// ---------------------------------------------------------------------------
// Pre-pass: W f32 [NB][GG][DD] -> bf16 swizzled per-bin images in d_ws.
// Image layout == exactly what the main kernel's LDS wants after a LINEAR
// copy: byte off = row*256 + ((granule*16) ^ ((row&7)<<4)), rows >=GG zeroed.
// One thread per 16B granule: a row is 16 granules -> 200*112*16 = 358400.
// (Round-3 bug: used 8 granules/row, leaving the upper half of every W row
//  unwritten poison -> absmax 4.19. Fixed to 16.)
// ---------------------------------------------------------------------------
__global__ __launch_bounds__(256) void wconv_kernel(
    const float* __restrict__ W, unsigned char* __restrict__ ws)
{
    const int gidx = blockIdx.x * 256 + threadIdx.x;
    if (gidx >= NB * WROWS * 16) return;
    const int gr  = gidx & 15;            // granule within row (8 elems = 16 B)
    const int row = (gidx >> 4) % WROWS;  // padded gene row
    const int n   = gidx / (WROWS * 16);
    int4 pack = make_int4(0, 0, 0, 0);
    if (row < GG) {
        const float* src = W + ((size_t)n * GG + row) * DD + gr * 8;
        const f32x4 a = *reinterpret_cast<const f32x4*>(src);
        const f32x4 b = *reinterpret_cast<const f32x4*>(src + 4);
        pack.x = f2bf_pack(a[0], a[1]);
        pack.y = f2bf_pack(a[2], a[3]);
        pack.z = f2bf_pack(b[0], b[1]);
        pack.w = f2bf_pack(b[2], b[3]);
    }
    const int off = row * ROWB + ((gr * 16) ^ ((row & 7) << 4));
    *reinterpret_cast<int4*>(ws + (size_t)n * WIMG + off) = pack;
}

// ---------------------------------------------------------------------------
// Main: bin n = blockIdx.y, 128 batch rows = blockIdx.x*128, 4 waves x 32 rows.
// K=128 fully unrolled (4 MFMA k-steps), G covered by 7 col-frags (last masked).
// ---------------------------------------------------------------------------
template <bool USE_WS>
__global__ __launch_bounds__(256, 4) void mtl_heads_kernel(
    const float* __restrict__ X,       // [B][NB][DD]
    const float* __restrict__ W,       // [NB][GG][DD]   (fallback path)
    const float* __restrict__ Bias,    // [NB][GG]
    const unsigned char* __restrict__ WS,  // swizzled bf16 images
    float* __restrict__ Out)           // [NB][B][GG]
{
    const int n     = blockIdx.y;
    const int mtile = blockIdx.x;
    const int tid   = threadIdx.x;
    const int lane  = tid & 63;
    const int wid   = tid >> 6;
    const int l15   = lane & 15;
    const int lhi   = lane >> 4;   // 0..3

    __shared__ __align__(16) char smem[WIMG];   // 28 KB: W tile, then epilogue scratch

    // ---- Stage W[n] into LDS (issue first, completes under the barrier) ----
    if (USE_WS) {
        // linear 28672 B copy, 28 wave-chunks of 1024 B: zero VGPR round-trip
        const unsigned char* src = WS + (size_t)n * WIMG;
        #pragma unroll
        for (int i = 0; i < 7; ++i) {
            const int c = i * 4 + wid;                    // wave-chunk 0..27
            gload_lds16(src + c * 1024 + lane * 16, smem + c * 1024);
        }
    } else {
        const int rsub = tid >> 4;          // 0..15
        const int k0   = (tid & 15) * 8;    // element offset
        #pragma unroll
        for (int it = 0; it < 7; ++it) {
            const int row = it * 16 + rsub; // 0..111
            int4 pack = make_int4(0, 0, 0, 0);
            if (row < GG) {
                const float* s = W + ((size_t)n * GG + row) * DD + k0;
                const f32x4 a = *reinterpret_cast<const f32x4*>(s);
                const f32x4 b = *reinterpret_cast<const f32x4*>(s + 4);
                pack.x = f2bf_pack(a[0], a[1]);
                pack.y = f2bf_pack(a[2], a[3]);
                pack.z = f2bf_pack(b[0], b[1]);
                pack.w = f2bf_pack(b[2], b[3]);
            }
            const int off = row * ROWB + ((k0 * 2) ^ ((row & 7) << 4));
            *reinterpret_cast<int4*>(smem + off) = pack;
        }
    }

    // ---- A fragments + bias: issued BEFORE the barrier (overlaps W staging) ----
    const int rowbase = mtile * 128 + wid * 32;
    short8 areg[2][4];
    #pragma unroll
    for (int rf = 0; rf < 2; ++rf) {
        const float* xrow = X + ((size_t)(rowbase + rf * 16 + l15) * NB + n) * DD + lhi * 8;
        #pragma unroll
        for (int ks = 0; ks < 4; ++ks) {
            const f32x4 a = *reinterpret_cast<const f32x4*>(xrow + ks * 32);
            const f32x4 b = *reinterpret_cast<const f32x4*>(xrow + ks * 32 + 4);
            int4 pk;
            pk.x = f2bf_pack(a[0], a[1]);
            pk.y = f2bf_pack(a[2], a[3]);
            pk.z = f2bf_pack(b[0], b[1]);
            pk.w = f2bf_pack(b[2], b[3]);
            areg[rf][ks] = __builtin_bit_cast(short8, pk);
        }
    }
    float bias[7];
    #pragma unroll
    for (int cf = 0; cf < 7; ++cf) {
        const int g = cf * 16 + l15;
        bias[cf] = (g < GG) ? Bias[n * GG + g] : 0.0f;
    }

    __syncthreads();   // barrier #1: drains staging (vmcnt+lgkmcnt)

    // ---- MFMA main: 2 row-frags x 7 col-frags x 4 k-steps = 56 MFMA/wave ----
    f32x4 acc[2][7];
    #pragma unroll
    for (int rf = 0; rf < 2; ++rf)
        #pragma unroll
        for (int cf = 0; cf < 7; ++cf)
            acc[rf][cf] = (f32x4){0.f, 0.f, 0.f, 0.f};

    #pragma unroll
    for (int cf = 0; cf < 7; ++cf) {
        const int g    = cf * 16 + l15;      // B-frag: gene row of W
        const int rowb = g * ROWB;
        const int swz  = (g & 7) << 4;
        #pragma unroll
        for (int ks = 0; ks < 4; ++ks) {
            const int off = rowb + (((lhi * 16) + ks * 64) ^ swz);
            const int4 braw = *reinterpret_cast<const int4*>(smem + off);  // ds_read_b128
            const short8 bfrag = __builtin_bit_cast(short8, braw);
            acc[0][cf] = __builtin_amdgcn_mfma_f32_16x16x32_bf16(areg[0][ks], bfrag, acc[0][cf], 0, 0, 0);
            acc[1][cf] = __builtin_amdgcn_mfma_f32_16x16x32_bf16(areg[1][ks], bfrag, acc[1][cf], 0, 0, 0);
        }
    }

    __syncthreads();   // barrier #2: all waves done reading W -> smem reusable

    // ---- Epilogue: per-wave LDS transpose -> contiguous dwordx4 stores ----
    // Wave-private region: [16 rows][100 f32] = 6400 B at smem + wid*6400.
    // C/D layout: col = l&15 (gene), row = lhi*4 + j.
    float* lds_f = reinterpret_cast<float*>(smem + wid * 6400);
    #pragma unroll
    for (int rf = 0; rf < 2; ++rf) {
        #pragma unroll
        for (int cf = 0; cf < 7; ++cf) {
            const int g = cf * 16 + l15;
            if (g < GG) {
                #pragma unroll
                for (int j = 0; j < 4; ++j)
                    lds_f[(lhi * 4 + j) * GG + g] = acc[rf][cf][j] + bias[cf];
            }
        }
        WAIT_LGKM0();   // wave-private region: wave-level sync suffices

        const char* rgn = smem + wid * 6400;
        char* dst = (char*)(Out + ((size_t)n * BSZ + rowbase + rf * 16) * GG);
        #pragma unroll
        for (int it = 0; it < 7; ++it) {
            const int c = it * 64 + lane;        // 16B-chunk index, 400 total
            if (c < 400) {
                const int4 v = *reinterpret_cast<const int4*>(rgn + c * 16);
                *reinterpret_cast<int4*>(dst + c * 16) = v;   // 1KB/wave, line-aligned
            }
        }
        WAIT_LGKM0();   // reads done before rf=1 overwrites the region
    }
}

extern "C" void kernel_launch(void* const* d_in, const int* in_sizes, int n_in,
                              void* d_out, int out_size, void* d_ws, size_t ws_size,
                              hipStream_t stream) {
    (void)in_sizes; (void)n_in; (void)out_size;
    const float* X    = (const float*)d_in[0];
    const float* W    = (const float*)d_in[1];
    const float* Bias = (const float*)d_in[2];
    float* Out        = (float*)d_out;
    dim3 grid(BSZ / 128, NB);   // 16 x 200 = 3200 blocks
    const size_t wsneed = (size_t)NB * WIMG;   // 5,734,400 B
    if (ws_size >= wsneed) {
        wconv_kernel<<<(NB * WROWS * 16 + 255) / 256, 256, 0, stream>>>(W, (unsigned char*)d_ws);
        mtl_heads_kernel<true><<<grid, 256, 0, stream>>>(X, W, Bias, (const unsigned char*)d_ws, Out);
    } else {
        mtl_heads_kernel<false><<<grid, 256, 0, stream>>>(X, W, Bias, nullptr, Out);
    }
}